// Round 2
// baseline (1228.510 us; speedup 1.0000x reference)
//
#include <hip/hip_runtime.h>

#define NN 65536
#define NE 1048576
#define NODE_F 32
#define EDGE_F 8
#define HID 64
#define NBATCH 64

// ---------------- support = x @ W   (x:[N,K], W:[K,64]) ----------------
template<int K>
__global__ __launch_bounds__(256) void node_linear(const float* __restrict__ x,
                                                   const float* __restrict__ W,
                                                   float* __restrict__ out, int n_nodes) {
    const int lane = threadIdx.x & 63;
    const int wv = threadIdx.x >> 6;
    float wr[K];
#pragma unroll
    for (int k = 0; k < K; ++k) wr[k] = W[k * HID + lane];
    int wid = blockIdx.x * 4 + wv;
    const int nw = gridDim.x * 4;
    for (int n0 = wid; n0 < n_nodes; n0 += nw) {
        const int n = __builtin_amdgcn_readfirstlane(n0);
        const float* xr = x + (size_t)n * K;
        float acc = 0.f;
#pragma unroll
        for (int k = 0; k < K; ++k) acc = fmaf(xr[k], wr[k], acc);
        out[(size_t)n * HID + lane] = acc;
    }
}

// ---------------- CSR build ----------------
__global__ __launch_bounds__(256) void hist_kernel(const int* __restrict__ Etgt, int* __restrict__ counts) {
    int i = blockIdx.x * 256 + threadIdx.x;
    const int stride = gridDim.x * 256;
    for (; i < NE; i += stride) atomicAdd(&counts[Etgt[i]], 1);
}

__global__ __launch_bounds__(1024) void scan_offsets(const int* __restrict__ counts,
                                                     int* __restrict__ offs, int* __restrict__ cursor) {
    __shared__ int part[1024];
    const int t = threadIdx.x;
    const int base = t * 64;
    int s = 0;
#pragma unroll 8
    for (int j = 0; j < 64; ++j) s += counts[base + j];
    part[t] = s;
    __syncthreads();
    for (int d = 1; d < 1024; d <<= 1) {
        int v = part[t];
        int vo = (t >= d) ? part[t - d] : 0;
        __syncthreads();
        part[t] = v + vo;
        __syncthreads();
    }
    int run = (t == 0) ? 0 : part[t - 1];
    for (int j = 0; j < 64; ++j) {
        int c = counts[base + j];
        offs[base + j] = run;
        cursor[base + j] = run;
        run += c;
    }
    if (t == 1023) offs[NN] = run;
}

__global__ __launch_bounds__(256) void fill_kernel(const int* __restrict__ Etgt, int* __restrict__ cursor,
                                                   int* __restrict__ edge_list) {
    int i = blockIdx.x * 256 + threadIdx.x;
    const int stride = gridDim.x * 256;
    for (; i < NE; i += stride) {
        const int p = atomicAdd(&cursor[Etgt[i]], 1);
        edge_list[p] = i;
    }
}

// ---------------- CSR edge-gated aggregation (layers 1 & 2) ----------------
// For node n: acc[lane] = sum_{e in in(n)} support[src(e)][lane] * enc_e[lane]
// enc_e = relu(ef[e] @ W1 + b1) @ W2 + b2 ; out = relu(acc + bias)
__global__ __launch_bounds__(256) void edge_conv_csr(
    const float* __restrict__ ef, const int* __restrict__ Esrc,
    const int* __restrict__ edge_list, const int* __restrict__ offs,
    const float* __restrict__ support,
    const float* __restrict__ W1, const float* __restrict__ b1,
    const float* __restrict__ W2, const float* __restrict__ b2,
    const float* __restrict__ bias,
    float* __restrict__ xout)
{
    __shared__ float h_lds[4][64];
    const int lane = threadIdx.x & 63;
    const int wv = threadIdx.x >> 6;
    float w1r[EDGE_F];
#pragma unroll
    for (int k = 0; k < EDGE_F; ++k) w1r[k] = W1[k * HID + lane];
    float w2r[HID];
#pragma unroll
    for (int k = 0; k < HID; ++k) w2r[k] = W2[k * HID + lane];
    const float b1v = b1[lane];
    const float b2v = b2[lane];
    const float bv = bias[lane];

    int wid = blockIdx.x * 4 + wv;
    const int nw = gridDim.x * 4;
    for (int n0 = wid; n0 < NN; n0 += nw) {
        const int n = __builtin_amdgcn_readfirstlane(n0);
        const int beg = __builtin_amdgcn_readfirstlane(offs[n]);
        const int end = __builtin_amdgcn_readfirstlane(offs[n + 1]);
        float acc = 0.f;
        for (int i = beg; i < end; ++i) {
            const int e = __builtin_amdgcn_readfirstlane(edge_list[i]);
            const int src = __builtin_amdgcn_readfirstlane(Esrc[e]);
            const float* efr = ef + (size_t)e * EDGE_F;
            float h = b1v;
#pragma unroll
            for (int k = 0; k < EDGE_F; ++k) h = fmaf(efr[k], w1r[k], h);
            h_lds[wv][lane] = fmaxf(h, 0.f);
            float enc = b2v;
#pragma unroll
            for (int k = 0; k < HID; k += 4) {
                const float4 hv = *(const float4*)(&h_lds[wv][k]);
                enc = fmaf(hv.x, w2r[k + 0], enc);
                enc = fmaf(hv.y, w2r[k + 1], enc);
                enc = fmaf(hv.z, w2r[k + 2], enc);
                enc = fmaf(hv.w, w2r[k + 3], enc);
            }
            const float sv = support[(size_t)src * HID + lane];
            acc = fmaf(sv, enc, acc);
        }
        xout[(size_t)n * HID + lane] = fmaxf(acc + bv, 0.f);
    }
}

// ---------------- support3[n] = x[n,:] . w  (w:[64]) ----------------
__global__ __launch_bounds__(256) void node_dot(const float* __restrict__ x, const float* __restrict__ w,
                                                float* __restrict__ out, int n_nodes) {
    const int lane = threadIdx.x & 63;
    const int wv = threadIdx.x >> 6;
    const float wk = w[lane];
    int wid = blockIdx.x * 4 + wv;
    const int nw = gridDim.x * 4;
    for (int n = wid; n < n_nodes; n += nw) {
        float v = x[(size_t)n * HID + lane] * wk;
#pragma unroll
        for (int off = 32; off >= 1; off >>= 1) v += __shfl_xor(v, off, 64);
        if (lane == 0) out[n] = v;
    }
}

// ---------------- layer-3 edge pass + batch pooling fused ----------------
// per node n: a3 = sum_{e in in(n)} sup3[src]*enc_e (scalar); atomicAdd(out[batch[n]], a3 + b_out)
__global__ __launch_bounds__(256) void edge_out_pool(
    const float* __restrict__ ef, const int* __restrict__ Esrc,
    const int* __restrict__ edge_list, const int* __restrict__ offs,
    const float* __restrict__ sup3,
    const float* __restrict__ W1, const float* __restrict__ b1,
    const float* __restrict__ W2, const float* __restrict__ b2,
    const int* __restrict__ batch, const float* __restrict__ b_out,
    float* __restrict__ out)
{
    const int lane = threadIdx.x & 63;
    const int wv = threadIdx.x >> 6;
    float w[8];
#pragma unroll
    for (int k = 0; k < 8; ++k) w[k] = W1[k];
    const float b1v = b1[0], w2 = W2[0], b2v = b2[0], bo = b_out[0];

    int wid = blockIdx.x * 4 + wv;
    const int nw = gridDim.x * 4;
    for (int n0 = wid; n0 < NN; n0 += nw) {
        const int n = __builtin_amdgcn_readfirstlane(n0);
        const int beg = __builtin_amdgcn_readfirstlane(offs[n]);
        const int end = __builtin_amdgcn_readfirstlane(offs[n + 1]);
        float acc = 0.f;
        for (int i = beg + lane; i < end; i += 64) {
            const int e = edge_list[i];
            const int src = Esrc[e];
            const float4 a = *(const float4*)(ef + (size_t)e * 8);
            const float4 c = *(const float4*)(ef + (size_t)e * 8 + 4);
            float h = b1v;
            h = fmaf(a.x, w[0], h); h = fmaf(a.y, w[1], h);
            h = fmaf(a.z, w[2], h); h = fmaf(a.w, w[3], h);
            h = fmaf(c.x, w[4], h); h = fmaf(c.y, w[5], h);
            h = fmaf(c.z, w[6], h); h = fmaf(c.w, w[7], h);
            const float enc = fmaxf(h, 0.f) * w2 + b2v;
            acc = fmaf(sup3[src], enc, acc);
        }
#pragma unroll
        for (int off = 32; off >= 1; off >>= 1) acc += __shfl_xor(acc, off, 64);
        if (lane == 0) atomicAdd(&out[batch[n]], acc + bo);
    }
}

extern "C" void kernel_launch(void* const* d_in, const int* in_sizes, int n_in,
                              void* d_out, int out_size, void* d_ws, size_t ws_size,
                              hipStream_t stream) {
    const float* nf    = (const float*)d_in[0];
    const float* ef    = (const float*)d_in[1];
    const int*   Esrc  = (const int*)d_in[2];
    const int*   Etgt  = (const int*)d_in[3];
    const int*   batch = (const int*)d_in[4];
    const float* W_in  = (const float*)d_in[5];
    const float* b_in  = (const float*)d_in[6];
    const float* W_mid = (const float*)d_in[7];
    const float* b_mid = (const float*)d_in[8];
    const float* W_out = (const float*)d_in[9];
    const float* b_out = (const float*)d_in[10];
    const float* eiW1  = (const float*)d_in[11];
    const float* eib1  = (const float*)d_in[12];
    const float* eiW2  = (const float*)d_in[13];
    const float* eib2  = (const float*)d_in[14];
    const float* emW1  = (const float*)d_in[15];
    const float* emb1  = (const float*)d_in[16];
    const float* emW2  = (const float*)d_in[17];
    const float* emb2  = (const float*)d_in[18];
    const float* eoW1  = (const float*)d_in[19];
    const float* eob1  = (const float*)d_in[20];
    const float* eoW2  = (const float*)d_in[21];
    const float* eob2  = (const float*)d_in[22];

    float* bufA = (float*)d_ws;                       // support [N,64] 16MB
    float* bufB = bufA + (size_t)NN * HID;            // x       [N,64] 16MB
    float* sup3 = bufB + (size_t)NN * HID;            // [N]
    int* counts = (int*)(sup3 + NN);                  // [N]
    int* offs   = counts + NN;                        // [N+1]
    int* cursor = offs + NN + 1;                      // [N]
    int* edge_list = cursor + NN;                     // [NE] 4MB

    hipMemsetAsync(d_out, 0, NBATCH * sizeof(float), stream);
    hipMemsetAsync(counts, 0, NN * sizeof(int), stream);

    // CSR by target (reused by all 3 layers)
    hist_kernel<<<1024, 256, 0, stream>>>(Etgt, counts);
    scan_offsets<<<1, 1024, 0, stream>>>(counts, offs, cursor);
    fill_kernel<<<1024, 256, 0, stream>>>(Etgt, cursor, edge_list);

    // layer 1
    node_linear<NODE_F><<<1024, 256, 0, stream>>>(nf, W_in, bufA, NN);
    edge_conv_csr<<<2048, 256, 0, stream>>>(ef, Esrc, edge_list, offs, bufA,
                                            eiW1, eib1, eiW2, eib2, b_in, bufB);
    // layer 2
    node_linear<HID><<<1024, 256, 0, stream>>>(bufB, W_mid, bufA, NN);
    edge_conv_csr<<<2048, 256, 0, stream>>>(ef, Esrc, edge_list, offs, bufA,
                                            emW1, emb1, emW2, emb2, b_mid, bufB);
    // layer 3 + pooling
    node_dot<<<256, 256, 0, stream>>>(bufB, W_out, sup3, NN);
    edge_out_pool<<<1024, 256, 0, stream>>>(ef, Esrc, edge_list, offs, sup3,
                                            eoW1, eob1, eoW2, eob2, batch, b_out, (float*)d_out);
}

// Round 3
// 691.568 us; speedup vs baseline: 1.7764x; 1.7764x over previous
//
#include <hip/hip_runtime.h>

#define NN 65536
#define NE 1048576
#define NODE_F 32
#define EDGE_F 8
#define HID 64
#define NBATCH 64
#define EPW 128   // edges per wave strip (NE/EPW = 8192 waves)

// ---------------- support = act(x) @ W  (x:[N,K], W:[K,64]) ----------------
// RELUB: x_eff = relu(x + pb) fused from previous layer's bias.
template<int K, bool RELUB>
__global__ __launch_bounds__(256) void node_linear(const float* __restrict__ x,
                                                   const float* __restrict__ pb,
                                                   const float* __restrict__ W,
                                                   float* __restrict__ out, int n_nodes) {
    const int lane = threadIdx.x & 63;
    const int wv = threadIdx.x >> 6;
    float wr[K];
#pragma unroll
    for (int k = 0; k < K; ++k) wr[k] = W[k * HID + lane];
    int wid = blockIdx.x * 4 + wv;
    const int nw = gridDim.x * 4;
    for (int n0 = wid; n0 < n_nodes; n0 += nw) {
        const int n = __builtin_amdgcn_readfirstlane(n0);
        const float* xr = x + (size_t)n * K;
        float acc = 0.f;
#pragma unroll
        for (int k = 0; k < K; ++k) {
            float xk = xr[k];
            if (RELUB) xk = fmaxf(xk + pb[k], 0.f);
            acc = fmaf(xk, wr[k], acc);
        }
        out[(size_t)n * HID + lane] = acc;
    }
}

// ---------------- CSR build ----------------
__global__ __launch_bounds__(256) void hist_kernel(const int* __restrict__ Etgt, int* __restrict__ counts) {
    int i = blockIdx.x * 256 + threadIdx.x;
    const int stride = gridDim.x * 256;
    for (; i < NE; i += stride) atomicAdd(&counts[Etgt[i]], 1);
}

__global__ __launch_bounds__(1024) void scan_offsets(const int* __restrict__ counts,
                                                     int* __restrict__ cursor) {
    __shared__ int part[1024];
    const int t = threadIdx.x;
    const int base = t * 64;
    int s = 0;
#pragma unroll 8
    for (int j = 0; j < 64; ++j) s += counts[base + j];
    part[t] = s;
    __syncthreads();
    for (int d = 1; d < 1024; d <<= 1) {
        int v = part[t];
        int vo = (t >= d) ? part[t - d] : 0;
        __syncthreads();
        part[t] = v + vo;
        __syncthreads();
    }
    int run = (t == 0) ? 0 : part[t - 1];
    for (int j = 0; j < 64; ++j) {
        cursor[base + j] = run;
        run += counts[base + j];
    }
}

// fill + permute: write edge data in target-sorted order.
// ef reads are COALESCED (i linear); permuted writes are scattered (fire-and-forget).
__global__ __launch_bounds__(256) void fill_permute(
    const int* __restrict__ Etgt, const int* __restrict__ Esrc, const float* __restrict__ ef,
    int* __restrict__ cursor, float* __restrict__ ef_perm,
    int* __restrict__ src_perm, int* __restrict__ tgt_perm)
{
    int i = blockIdx.x * 256 + threadIdx.x;
    const int stride = gridDim.x * 256;
    for (; i < NE; i += stride) {
        const int t = Etgt[i];
        const int p = atomicAdd(&cursor[t], 1);
        src_perm[p] = Esrc[i];
        tgt_perm[p] = t;
        const float4 a = *(const float4*)(ef + (size_t)i * 8);
        const float4 c = *(const float4*)(ef + (size_t)i * 8 + 4);
        *(float4*)(ef_perm + (size_t)p * 8) = a;
        *(float4*)(ef_perm + (size_t)p * 8 + 4) = c;
    }
}

// ---------------- strip-segmented edge-gated aggregation (layers 1 & 2) ----
// Wave owns EPW sorted edges. acc[lane] in registers; flush on tgt change.
// Interior segments: exclusive -> plain store. Strip-boundary segments: atomicAdd.
__global__ __launch_bounds__(256) void edge_strip(
    const float* __restrict__ ef_perm, const int* __restrict__ src_perm,
    const int* __restrict__ tgt_perm, const float* __restrict__ support,
    const float* __restrict__ W1, const float* __restrict__ b1,
    const float* __restrict__ W2, const float* __restrict__ b2,
    float* __restrict__ agg)
{
    __shared__ float h_lds[4][2][64];
    const int lane = threadIdx.x & 63;
    const int wv = threadIdx.x >> 6;
    float w1r[EDGE_F];
#pragma unroll
    for (int k = 0; k < EDGE_F; ++k) w1r[k] = W1[k * HID + lane];
    float w2r[HID];
#pragma unroll
    for (int k = 0; k < HID; ++k) w2r[k] = W2[k * HID + lane];
    const float b1v = b1[lane];
    const float b2v = b2[lane];

    const int wid = __builtin_amdgcn_readfirstlane(blockIdx.x * 4 + wv);
    const size_t base = (size_t)wid * EPW;
    int tgt_prev = __builtin_amdgcn_readfirstlane(tgt_perm[base]);
    int first = 1;
    float acc = 0.f;

#pragma unroll 2
    for (int j = 0; j < EPW; ++j) {
        const size_t i = base + j;
        const int tgt = __builtin_amdgcn_readfirstlane(tgt_perm[i]);
        const int src = __builtin_amdgcn_readfirstlane(src_perm[i]);
        const float* efr = ef_perm + i * 8;          // uniform addr -> s_load
        float h = b1v;
#pragma unroll
        for (int k = 0; k < EDGE_F; ++k) h = fmaf(efr[k], w1r[k], h);
        const float sv = support[(size_t)src * HID + lane];   // coalesced 256B row
        if (tgt != tgt_prev) {                        // wave-uniform branch
            float* dst = agg + (size_t)tgt_prev * HID + lane;
            if (first) { atomicAdd(dst, acc); first = 0; }
            else *dst = acc;
            acc = 0.f;
            tgt_prev = tgt;
        }
        h_lds[wv][j & 1][lane] = fmaxf(h, 0.f);
        float enc = b2v;
#pragma unroll
        for (int k = 0; k < HID; k += 4) {            // broadcast reads, conflict-free
            const float4 hv = *(const float4*)(&h_lds[wv][j & 1][k]);
            enc = fmaf(hv.x, w2r[k + 0], enc);
            enc = fmaf(hv.y, w2r[k + 1], enc);
            enc = fmaf(hv.z, w2r[k + 2], enc);
            enc = fmaf(hv.w, w2r[k + 3], enc);
        }
        acc = fmaf(sv, enc, acc);
    }
    atomicAdd(agg + (size_t)tgt_prev * HID + lane, acc);
}

// ---------------- sup3[n] = relu(x[n,:]+pb) . w ----------------
__global__ __launch_bounds__(256) void node_dot(const float* __restrict__ x, const float* __restrict__ pb,
                                                const float* __restrict__ w,
                                                float* __restrict__ out, int n_nodes) {
    const int lane = threadIdx.x & 63;
    const int wv = threadIdx.x >> 6;
    const float wk = w[lane];
    const float pbv = pb[lane];
    int wid = blockIdx.x * 4 + wv;
    const int nw = gridDim.x * 4;
    for (int n = wid; n < n_nodes; n += nw) {
        float v = fmaxf(x[(size_t)n * HID + lane] + pbv, 0.f) * wk;
#pragma unroll
        for (int off = 32; off >= 1; off >>= 1) v += __shfl_xor(v, off, 64);
        if (lane == 0) out[n] = v;
    }
}

// ---------------- layer-3 edge pass (scalar, edge-parallel, coalesced ef) ----
__global__ __launch_bounds__(256) void edge_conv_out(
    const float* __restrict__ ef, const int* __restrict__ Esrc, const int* __restrict__ Etgt,
    const float* __restrict__ support,
    const float* __restrict__ W1, const float* __restrict__ b1,
    const float* __restrict__ W2, const float* __restrict__ b2,
    float* __restrict__ agg)
{
    int e = blockIdx.x * 256 + threadIdx.x;
    const int stride = gridDim.x * 256;
    float w[8];
#pragma unroll
    for (int k = 0; k < 8; ++k) w[k] = W1[k];
    const float b1v = b1[0], w2 = W2[0], b2v = b2[0];
    for (; e < NE; e += stride) {
        const float4 a = *(const float4*)(ef + (size_t)e * 8);
        const float4 c = *(const float4*)(ef + (size_t)e * 8 + 4);
        float h = b1v;
        h = fmaf(a.x, w[0], h); h = fmaf(a.y, w[1], h);
        h = fmaf(a.z, w[2], h); h = fmaf(a.w, w[3], h);
        h = fmaf(c.x, w[4], h); h = fmaf(c.y, w[5], h);
        h = fmaf(c.z, w[6], h); h = fmaf(c.w, w[7], h);
        const float enc = fmaxf(h, 0.f) * w2 + b2v;
        const float msg = support[Esrc[e]] * enc;
        atomicAdd(&agg[Etgt[e]], msg);
    }
}

// ---------------- batch sum-pool ----------------
__global__ __launch_bounds__(256) void pool(const float* __restrict__ agg, const int* __restrict__ batch,
                                            const float* __restrict__ b_out, float* __restrict__ out) {
    const int n = blockIdx.x * 256 + threadIdx.x;
    const int lane = threadIdx.x & 63;
    float v = agg[n] + b_out[0];
    const int b = batch[n];
    const int b0 = __shfl(b, 0, 64);
    if (__all(b == b0)) {
#pragma unroll
        for (int off = 32; off >= 1; off >>= 1) v += __shfl_xor(v, off, 64);
        if (lane == 0) atomicAdd(&out[b0], v);
    } else {
        atomicAdd(&out[b], v);
    }
}

extern "C" void kernel_launch(void* const* d_in, const int* in_sizes, int n_in,
                              void* d_out, int out_size, void* d_ws, size_t ws_size,
                              hipStream_t stream) {
    const float* nf    = (const float*)d_in[0];
    const float* ef    = (const float*)d_in[1];
    const int*   Esrc  = (const int*)d_in[2];
    const int*   Etgt  = (const int*)d_in[3];
    const int*   batch = (const int*)d_in[4];
    const float* W_in  = (const float*)d_in[5];
    const float* b_in  = (const float*)d_in[6];
    const float* W_mid = (const float*)d_in[7];
    const float* b_mid = (const float*)d_in[8];
    const float* W_out = (const float*)d_in[9];
    const float* b_out = (const float*)d_in[10];
    const float* eiW1  = (const float*)d_in[11];
    const float* eib1  = (const float*)d_in[12];
    const float* eiW2  = (const float*)d_in[13];
    const float* eib2  = (const float*)d_in[14];
    const float* emW1  = (const float*)d_in[15];
    const float* emb1  = (const float*)d_in[16];
    const float* emW2  = (const float*)d_in[17];
    const float* emb2  = (const float*)d_in[18];
    const float* eoW1  = (const float*)d_in[19];
    const float* eob1  = (const float*)d_in[20];
    const float* eoW2  = (const float*)d_in[21];
    const float* eob2  = (const float*)d_in[22];

    float* bufA    = (float*)d_ws;                    // support [N,64] 16MB
    float* bufB    = bufA + (size_t)NN * HID;         // agg/x   [N,64] 16MB
    float* sup3    = bufB + (size_t)NN * HID;         // [N]
    float* agg3    = sup3 + NN;                       // [N]
    float* ef_perm = agg3 + NN;                       // [NE,8] 32MB
    int* counts    = (int*)(ef_perm + (size_t)NE * 8);// [N]
    int* cursor    = counts + NN;                     // [N]
    int* src_perm  = cursor + NN;                     // [NE] 4MB
    int* tgt_perm  = src_perm + NE;                   // [NE] 4MB

    hipMemsetAsync(d_out, 0, NBATCH * sizeof(float), stream);
    hipMemsetAsync(counts, 0, NN * sizeof(int), stream);

    // CSR-sorted edge arrays (reused by layers 1 & 2)
    hist_kernel<<<1024, 256, 0, stream>>>(Etgt, counts);
    scan_offsets<<<1, 1024, 0, stream>>>(counts, cursor);
    fill_permute<<<1024, 256, 0, stream>>>(Etgt, Esrc, ef, cursor, ef_perm, src_perm, tgt_perm);

    // layer 1
    node_linear<NODE_F, false><<<1024, 256, 0, stream>>>(nf, nullptr, W_in, bufA, NN);
    hipMemsetAsync(bufB, 0, (size_t)NN * HID * sizeof(float), stream);
    edge_strip<<<NE / EPW / 4, 256, 0, stream>>>(ef_perm, src_perm, tgt_perm, bufA,
                                                 eiW1, eib1, eiW2, eib2, bufB);
    // layer 2 (relu(x+b_in) fused into node_linear load)
    node_linear<HID, true><<<1024, 256, 0, stream>>>(bufB, b_in, W_mid, bufA, NN);
    hipMemsetAsync(bufB, 0, (size_t)NN * HID * sizeof(float), stream);
    edge_strip<<<NE / EPW / 4, 256, 0, stream>>>(ef_perm, src_perm, tgt_perm, bufA,
                                                 emW1, emb1, emW2, emb2, bufB);
    // layer 3 + pooling (relu(x+b_mid) fused into node_dot)
    node_dot<<<256, 256, 0, stream>>>(bufB, b_mid, W_out, sup3, NN);
    hipMemsetAsync(agg3, 0, NN * sizeof(float), stream);
    edge_conv_out<<<1024, 256, 0, stream>>>(ef, Esrc, Etgt, sup3, eoW1, eob1, eoW2, eob2, agg3);
    pool<<<NN / 256, 256, 0, stream>>>(agg3, batch, b_out, (float*)d_out);
}